// Round 1
// baseline (1054.969 us; speedup 1.0000x reference)
//
#include <hip/hip_runtime.h>
#include <cstdint>
#include <cstddef>

// LSTM cell: B=1024, D_IN=D_H=4096, fp32 inputs/outputs.
// Strategy: z[1024,16384] = A[1024,8192] @ Bpack[8192,16384] in bf16 MFMA,
// weights pre-transposed to Bt[n][k] (K-contiguous) so the GEMM is the
// verified m97 "B^T input" structure (global_load_lds width=16, 128x128 tile).

typedef __bf16 bf16;
typedef __bf16 bf16x8 __attribute__((ext_vector_type(8)));
typedef __bf16 bf16x4 __attribute__((ext_vector_type(4)));
typedef float f32x4 __attribute__((ext_vector_type(4)));

static constexpr int Bn = 1024;     // batch
static constexpr int DH = 4096;
static constexpr int K = 8192;      // 2*DH
static constexpr int N = 16384;     // 4*DH
static constexpr int BM = 128, BN = 128, BK = 32;

__device__ __forceinline__ void load_lds16(const void* g, void* l) {
  __builtin_amdgcn_global_load_lds(
      (const __attribute__((address_space(1))) unsigned int*)g,
      (__attribute__((address_space(3))) unsigned int*)l, 16, 0, 0);
}

// ---------------- kernel 1: pack A = [x | h_prev] -> bf16 [Bn][K] -------------
__global__ void pack_A(const float* __restrict__ x, const float* __restrict__ h,
                       bf16* __restrict__ A) {
  int idx4 = blockIdx.x * blockDim.x + threadIdx.x;   // one float4 position
  int b = idx4 >> 11;           // 2048 float4 per K-row
  int q = idx4 & 2047;
  int k = q << 2;
  const float* src = (k < DH) ? (x + (size_t)b * DH + k)
                              : (h + (size_t)b * DH + (k - DH));
  float4 v = *(const float4*)src;
  bf16x4 o;
  o[0] = (bf16)v.x; o[1] = (bf16)v.y; o[2] = (bf16)v.z; o[3] = (bf16)v.w;
  *(bf16x4*)(A + (size_t)idx4 * 4) = o;
}

// ------------- kernel 2: transpose+convert 8 weight mats -> Bt[n][k] ---------
// Bt row n_g = gate*4096 + n ; col k_g = isU*4096 + k ; value = M[k][n]
__global__ void conv_w(const float* __restrict__ Wi, const float* __restrict__ Ui,
                       const float* __restrict__ Wf, const float* __restrict__ Uf,
                       const float* __restrict__ Wg, const float* __restrict__ Ug,
                       const float* __restrict__ Wo, const float* __restrict__ Uo,
                       bf16* __restrict__ Bt) {
  __shared__ float tile[64][65];   // +1 pad: conflict-free-ish both phases
  int bz = blockIdx.z;
  int gate = bz >> 1, isU = bz & 1;
  const float* src;
  switch (bz) {
    case 0: src = Wi; break; case 1: src = Ui; break;
    case 2: src = Wf; break; case 3: src = Uf; break;
    case 4: src = Wg; break; case 5: src = Ug; break;
    default: src = (bz == 6) ? Wo : Uo; break;
  }
  int k0 = blockIdx.x * 64, n0 = blockIdx.y * 64;
  int t = threadIdx.x;
  int c = t & 15, r = t >> 4;
#pragma unroll
  for (int p = 0; p < 4; ++p) {
    float4 v = *(const float4*)(src + (size_t)(k0 + r + p * 16) * DH + n0 + c * 4);
    tile[r + p * 16][c * 4 + 0] = v.x;
    tile[r + p * 16][c * 4 + 1] = v.y;
    tile[r + p * 16][c * 4 + 2] = v.z;
    tile[r + p * 16][c * 4 + 3] = v.w;
  }
  __syncthreads();
  int nl = t >> 3, kc = (t & 7) * 8;
#pragma unroll
  for (int p = 0; p < 2; ++p) {
    int n_l = nl + p * 32;
    bf16x8 o;
#pragma unroll
    for (int i = 0; i < 8; ++i) o[i] = (bf16)tile[kc + i][n_l];
    size_t row = (size_t)(gate * DH + n0 + n_l);
    *(bf16x8*)(Bt + row * K + (size_t)(isU * DH + k0 + kc)) = o;
  }
}

// ---------------- kernel 3: bf16 GEMM (m97 structure), Z fp32 ----------------
__global__ __launch_bounds__(256) void gemm_bt(const bf16* __restrict__ A,
                                               const bf16* __restrict__ Bt,
                                               float* __restrict__ Z) {
  __shared__ __align__(16) bf16 As[BM * BK];   // [m][k], k contiguous, 8 KB
  __shared__ __align__(16) bf16 Bs[BN * BK];   // [n][k], k contiguous, 8 KB
  const int m0 = blockIdx.x * BM;   // m fastest-varying: B-slab L2 reuse
  const int n0 = blockIdx.y * BN;
  const int t = threadIdx.x;
  const int l = t & 63;
  const int w = t >> 6;
  const int lane15 = l & 15, quad = l >> 4;
  const int wm = w & 1, wn = w >> 1;
  // staging geometry: chunk c covers LDS bytes [c*1024, c*1024+1024)
  const int rc0 = (w * 2 + 0) * 16 + (l >> 2);
  const int rc1 = (w * 2 + 1) * 16 + (l >> 2);
  const int kk = (l & 3) * 8;

  f32x4 acc[4][4];
#pragma unroll
  for (int i = 0; i < 4; ++i)
#pragma unroll
    for (int j = 0; j < 4; ++j) acc[i][j] = (f32x4)0.0f;

  for (int kt = 0; kt < K / BK; ++kt) {
    const int k0 = kt * BK;
    load_lds16(A + (size_t)(m0 + rc0) * K + k0 + kk, (char*)As + (w * 2 + 0) * 1024);
    load_lds16(A + (size_t)(m0 + rc1) * K + k0 + kk, (char*)As + (w * 2 + 1) * 1024);
    load_lds16(Bt + (size_t)(n0 + rc0) * K + k0 + kk, (char*)Bs + (w * 2 + 0) * 1024);
    load_lds16(Bt + (size_t)(n0 + rc1) * K + k0 + kk, (char*)Bs + (w * 2 + 1) * 1024);
    __syncthreads();   // drains vmcnt -> LDS visible
    bf16x8 aF[4], bF[4];
#pragma unroll
    for (int i = 0; i < 4; ++i)
      aF[i] = *(const bf16x8*)(As + (wm * 64 + i * 16 + lane15) * BK + quad * 8);
#pragma unroll
    for (int j = 0; j < 4; ++j)
      bF[j] = *(const bf16x8*)(Bs + (wn * 64 + j * 16 + lane15) * BK + quad * 8);
#pragma unroll
    for (int i = 0; i < 4; ++i)
#pragma unroll
      for (int j = 0; j < 4; ++j)
        acc[i][j] = __builtin_amdgcn_mfma_f32_16x16x32_bf16(aF[i], bF[j], acc[i][j], 0, 0, 0);
    __syncthreads();   // compute done before next stage overwrites
  }
  // epilogue: C/D layout col=lane&15, row=quad*4+reg (m89/m91-verified)
#pragma unroll
  for (int i = 0; i < 4; ++i) {
    const int row = m0 + wm * 64 + i * 16 + quad * 4;
#pragma unroll
    for (int j = 0; j < 4; ++j) {
      const int col = n0 + wn * 64 + j * 16 + lane15;
#pragma unroll
      for (int r = 0; r < 4; ++r)
        Z[(size_t)(row + r) * N + col] = acc[i][j][r];
    }
  }
}

// ---------------- kernel 4: gates epilogue ----------------
__device__ __forceinline__ float sigm(float x) { return 1.0f / (1.0f + __expf(-x)); }
__device__ __forceinline__ float tanh_(float x) { return 1.0f - 2.0f / (__expf(2.0f * x) + 1.0f); }

__global__ void gates_k(const float* __restrict__ Z, const float* __restrict__ cp,
                        const float* __restrict__ bi, const float* __restrict__ bfv,
                        const float* __restrict__ bg, const float* __restrict__ bo,
                        float* __restrict__ out) {
  int idx4 = blockIdx.x * blockDim.x + threadIdx.x;   // 1M float4 positions
  int b = idx4 >> 10;       // 1024 float4 per DH row
  int q = idx4 & 1023;
  const float4* zr = (const float4*)(Z + (size_t)b * N);
  float4 vi = zr[q];
  float4 vf = zr[q + 1024];
  float4 vg = zr[q + 2048];
  float4 vo = zr[q + 3072];
  float4 ai = ((const float4*)bi)[q];
  float4 af = ((const float4*)bfv)[q];
  float4 ag = ((const float4*)bg)[q];
  float4 ao = ((const float4*)bo)[q];
  float4 vc = ((const float4*)cp)[idx4];
  float4 hv, cv;
  {
    float ig, fg, cc, og, c;
#define GATE(X)                                                      \
    ig = sigm(vi.X + ai.X); fg = sigm(vf.X + af.X);                  \
    cc = tanh_(vg.X + ag.X); og = sigm(vo.X + ao.X);                 \
    c = fg * vc.X + ig * cc; cv.X = c; hv.X = og * tanh_(c);
    GATE(x) GATE(y) GATE(z) GATE(w)
#undef GATE
  }
  ((float4*)out)[idx4] = hv;
  ((float4*)(out + (size_t)Bn * DH))[idx4] = cv;
}

// ---------------- launch ----------------
extern "C" void kernel_launch(void* const* d_in, const int* in_sizes, int n_in,
                              void* d_out, int out_size, void* d_ws, size_t ws_size,
                              hipStream_t stream) {
  const float* x  = (const float*)d_in[0];
  const float* hp = (const float*)d_in[1];
  const float* cp = (const float*)d_in[2];
  const float* Wi = (const float*)d_in[3];
  const float* Ui = (const float*)d_in[4];
  const float* bi = (const float*)d_in[5];
  const float* Wf = (const float*)d_in[6];
  const float* Uf = (const float*)d_in[7];
  const float* bf = (const float*)d_in[8];
  const float* Wg = (const float*)d_in[9];
  const float* Ug = (const float*)d_in[10];
  const float* bg = (const float*)d_in[11];
  const float* Wo = (const float*)d_in[12];
  const float* Uo = (const float*)d_in[13];
  const float* bo = (const float*)d_in[14];

  // ws layout: A bf16 16MB | Bt bf16 256MB | Z fp32 64MB  (336MB total)
  bf16* Aw = (bf16*)d_ws;
  bf16* Bt = (bf16*)((char*)d_ws + ((size_t)16 << 20));
  float* Z = (float*)((char*)d_ws + ((size_t)272 << 20));

  hipLaunchKernelGGL(pack_A, dim3((Bn * K / 4) / 256), dim3(256), 0, stream, x, hp, Aw);
  hipLaunchKernelGGL(conv_w, dim3(64, 64, 8), dim3(256), 0, stream,
                     Wi, Ui, Wf, Uf, Wg, Ug, Wo, Uo, Bt);
  hipLaunchKernelGGL(gemm_bt, dim3(Bn / BM, N / BN), dim3(256), 0, stream, Aw, Bt, Z);
  hipLaunchKernelGGL(gates_k, dim3((Bn * DH / 4) / 256), dim3(256), 0, stream,
                     Z, cp, bi, bf, bg, bo, (float*)d_out);
}

// Round 2
// 924.348 us; speedup vs baseline: 1.1413x; 1.1413x over previous
//
#include <hip/hip_runtime.h>
#include <cstdint>
#include <cstddef>

// LSTM cell: B=1024, D_IN=D_H=4096, fp32 in/out.
// z = [x|h] @ [[W],[U]] via bf16 MFMA. Bt[n'][k] gate-interleaved:
// n' = (hc>>4)*64 + gate*16 + (hc&15)  ->  per-block BN=64 slab holds all 4
// gates for 16 h-cols; GEMM epilogue computes gates/c/h in-register.
// BM=512 cuts Bt HBM refetch to x2 (was x8 -> 1.65 GB measured thrash).

typedef __bf16 bf16;
typedef __bf16 bf16x8 __attribute__((ext_vector_type(8)));
typedef __bf16 bf16x4 __attribute__((ext_vector_type(4)));
typedef float f32x4 __attribute__((ext_vector_type(4)));

static constexpr int Bn = 1024;   // batch
static constexpr int DH = 4096;
static constexpr int K  = 8192;   // 2*DH
static constexpr int BM = 512, BN = 64, BK = 32;

__device__ __forceinline__ void load_lds16(const void* g, void* l) {
  __builtin_amdgcn_global_load_lds(
      (const __attribute__((address_space(1))) unsigned int*)g,
      (__attribute__((address_space(3))) unsigned int*)l, 16, 0, 0);
}

// ---------------- kernel 1: pack A = [x | h_prev] -> bf16 [Bn][K] ------------
__global__ void pack_A(const float* __restrict__ x, const float* __restrict__ h,
                       bf16* __restrict__ A) {
  int idx4 = blockIdx.x * blockDim.x + threadIdx.x;   // one float4 position
  int b = idx4 >> 11;           // 2048 float4 per K-row
  int q = idx4 & 2047;
  int k = q << 2;
  const float* src = (k < DH) ? (x + (size_t)b * DH + k)
                              : (h + (size_t)b * DH + (k - DH));
  float4 v = *(const float4*)src;
  bf16x4 o;
  o[0] = (bf16)v.x; o[1] = (bf16)v.y; o[2] = (bf16)v.z; o[3] = (bf16)v.w;
  *(bf16x4*)(A + (size_t)idx4 * 4) = o;
}

// ---- kernel 2: transpose+convert weights -> gate-interleaved Bt[n'][k] ------
// 256k x 64n tile; bf16 LDS, XOR chunk swizzle; 512-B contiguous store runs.
__global__ __launch_bounds__(256) void conv_w2(
    const float* __restrict__ Wi, const float* __restrict__ Ui,
    const float* __restrict__ Wf, const float* __restrict__ Uf,
    const float* __restrict__ Wg, const float* __restrict__ Ug,
    const float* __restrict__ Wo, const float* __restrict__ Uo,
    bf16* __restrict__ Bt) {
  __shared__ short tile[64 * 256];   // 32 KB: [nl][k shorts], chunk-swizzled
  const int bz = blockIdx.z;
  const int gate = bz >> 1, isU = bz & 1;
  const float* src;
  switch (bz) {
    case 0: src = Wi; break; case 1: src = Ui; break;
    case 2: src = Wf; break; case 3: src = Uf; break;
    case 4: src = Wg; break; case 5: src = Ug; break;
    default: src = (bz == 6) ? Wo : Uo; break;
  }
  const int k0 = blockIdx.x * 256, n0 = blockIdx.y * 64;
  const int t = threadIdx.x;
  const int c = t & 15;        // float4 column within 64-col strip
  const int pr = t >> 4;       // row-pair 0..15
#pragma unroll
  for (int it = 0; it < 8; ++it) {
    const int R = it * 16 + pr;          // k-pair index 0..127
    const int k = 2 * R;
    float4 v0 = *(const float4*)(src + (size_t)(k0 + k) * DH + n0 + c * 4);
    float4 v1 = *(const float4*)(src + (size_t)(k0 + k + 1) * DH + n0 + c * 4);
    const int chunk = R >> 2, sub = R & 3;
#pragma unroll
    for (int i = 0; i < 4; ++i) {
      const int nl = c * 4 + i;
      bf16 lo = (bf16)((&v0.x)[i]);
      bf16 hi = (bf16)((&v1.x)[i]);
      short2 pk;
      pk.x = __builtin_bit_cast(short, lo);
      pk.y = __builtin_bit_cast(short, hi);
      // shorts offset: row nl*256 + swizzled 8-short chunk + sub-pair
      *(short2*)&tile[nl * 256 + ((chunk ^ (nl & 7)) << 3) + (sub << 1)] = pk;
    }
  }
  __syncthreads();
  const int u = t & 31;        // 16-B chunk along k
#pragma unroll
  for (int rr = 0; rr < 8; ++rr) {
    const int nl = rr * 8 + (t >> 5);
    bf16x8 val = *(const bf16x8*)&tile[nl * 256 + ((u ^ (nl & 7)) << 3)];
    const int hc = n0 + nl;
    const size_t row = (size_t)((hc >> 4) * 64 + gate * 16 + (hc & 15));
    *(bf16x8*)(Bt + row * K + (size_t)(isU * DH + k0 + 8 * u)) = val;
  }
}

// ------- kernel 3: fused GEMM + gates (BM=512, BN=64, 256 thr, 4 waves) ------
__device__ __forceinline__ float sigm(float x) { return 1.0f / (1.0f + __expf(-x)); }
__device__ __forceinline__ float tanh_(float x) { return 1.0f - 2.0f / (__expf(2.0f * x) + 1.0f); }

__global__ __launch_bounds__(256, 2) void lstm_gemm(
    const bf16* __restrict__ A, const bf16* __restrict__ Bt,
    const float* __restrict__ cp,
    const float* __restrict__ bi, const float* __restrict__ bfv,
    const float* __restrict__ bg, const float* __restrict__ bo,
    float* __restrict__ out) {
  __shared__ __align__(16) bf16 As[BM * BK];   // 32 KB, [m][k] k-contig
  __shared__ __align__(16) bf16 Bs[BN * BK];   // 4 KB,  [n'][k] k-contig
  const int m0 = blockIdx.x * BM;
  const int n0 = blockIdx.y * BN;              // Bt row base (gate-interleaved)
  const int t = threadIdx.x, l = t & 63, w = t >> 6;
  const int lane15 = l & 15, quad = l >> 4;
  const int srow = l >> 2;          // staging row within 16-row chunk
  const int skk = (l & 3) * 8;      // staging k-elem offset

  f32x4 acc[8][4];
#pragma unroll
  for (int i = 0; i < 8; ++i)
#pragma unroll
    for (int j = 0; j < 4; ++j) acc[i][j] = (f32x4)0.0f;

  for (int kt = 0; kt < K / BK; ++kt) {
    const int k0 = kt * BK;
    // A: 32 chunks of 16 rows; wave w stages chunks w*8..w*8+7
#pragma unroll
    for (int cc = 0; cc < 8; ++cc) {
      const int row = m0 + w * 128 + cc * 16 + srow;
      load_lds16(A + (size_t)row * K + k0 + skk, (char*)As + (w * 8 + cc) * 1024);
    }
    // B: 4 chunks; wave w stages chunk w
    load_lds16(Bt + (size_t)(n0 + w * 16 + srow) * K + k0 + skk, (char*)Bs + w * 1024);
    __syncthreads();
    bf16x8 aF[8], bF[4];
#pragma unroll
    for (int i = 0; i < 8; ++i)
      aF[i] = *(const bf16x8*)(As + (w * 128 + i * 16 + lane15) * BK + quad * 8);
#pragma unroll
    for (int j = 0; j < 4; ++j)
      bF[j] = *(const bf16x8*)(Bs + (j * 16 + lane15) * BK + quad * 8);
#pragma unroll
    for (int i = 0; i < 8; ++i)
#pragma unroll
      for (int j = 0; j < 4; ++j)
        acc[i][j] = __builtin_amdgcn_mfma_f32_16x16x32_bf16(aF[i], bF[j], acc[i][j], 0, 0, 0);
    __syncthreads();
  }

  // Fused epilogue: lane's column j IS the gate (i,f,g,o); hc fixed per lane.
  const int hc = blockIdx.y * 16 + lane15;
  const float vbi = bi[hc], vbf = bfv[hc], vbg = bg[hc], vbo = bo[hc];
  float* outh = out;
  float* outc = out + (size_t)Bn * DH;
#pragma unroll
  for (int i = 0; i < 8; ++i) {
    const int brow = m0 + w * 128 + i * 16 + quad * 4;
#pragma unroll
    for (int r = 0; r < 4; ++r) {
      const int b = brow + r;
      const float zi = acc[i][0][r] + vbi;
      const float zf = acc[i][1][r] + vbf;
      const float zg = acc[i][2][r] + vbg;
      const float zo = acc[i][3][r] + vbo;
      const float ig = sigm(zi), fg = sigm(zf), gg = tanh_(zg), og = sigm(zo);
      const float cprev = cp[(size_t)b * DH + hc];
      const float cnew = fg * cprev + ig * gg;
      outh[(size_t)b * DH + hc] = og * tanh_(cnew);
      outc[(size_t)b * DH + hc] = cnew;
    }
  }
}

// ---------------- launch ----------------
extern "C" void kernel_launch(void* const* d_in, const int* in_sizes, int n_in,
                              void* d_out, int out_size, void* d_ws, size_t ws_size,
                              hipStream_t stream) {
  const float* x  = (const float*)d_in[0];
  const float* hp = (const float*)d_in[1];
  const float* cp = (const float*)d_in[2];
  const float* Wi = (const float*)d_in[3];
  const float* Ui = (const float*)d_in[4];
  const float* bi = (const float*)d_in[5];
  const float* Wf = (const float*)d_in[6];
  const float* Uf = (const float*)d_in[7];
  const float* bf = (const float*)d_in[8];
  const float* Wg = (const float*)d_in[9];
  const float* Ug = (const float*)d_in[10];
  const float* bg = (const float*)d_in[11];
  const float* Wo = (const float*)d_in[12];
  const float* Uo = (const float*)d_in[13];
  const float* bo = (const float*)d_in[14];

  // ws: A bf16 16 MB | Bt bf16 256 MB  (272 MB total)
  bf16* Aw = (bf16*)d_ws;
  bf16* Bt = (bf16*)((char*)d_ws + ((size_t)16 << 20));

  hipLaunchKernelGGL(conv_w2, dim3(16, 64, 8), dim3(256), 0, stream,
                     Wi, Ui, Wf, Uf, Wg, Ug, Wo, Uo, Bt);
  hipLaunchKernelGGL(pack_A, dim3((Bn * K / 4) / 256), dim3(256), 0, stream, x, hp, Aw);
  hipLaunchKernelGGL(lstm_gemm, dim3(Bn / BM, (4 * DH) / BN), dim3(256), 0, stream,
                     Aw, Bt, cp, bi, bf, bg, bo, (float*)d_out);
}